// Round 10
// baseline (435.438 us; speedup 1.0000x reference)
//
#include <hip/hip_runtime.h>
#include <math.h>
#include <stdint.h>

typedef short bf16x8 __attribute__((ext_vector_type(8)));   // 8 bf16 (4 VGPRs)
typedef float f32x4 __attribute__((ext_vector_type(4)));

#define NFRAGS 36
#define T 2                 // point-tiles (16 pts) per wave
#define NW 4                // waves per block
#define BS 256
#define PTS_BLK (NW * T * 16)   // 128 points per pass
#define PASSES 2            // grid-stride passes per block

// RNE float -> bf16 bits (prologue only; weights keep full rounding quality)
__device__ __forceinline__ uint32_t f2bf_rne(float f) {
    uint32_t u = __float_as_uint(f);
    return (u + 0x7FFFu + ((u >> 16) & 1u)) >> 16;
}

// ---- hot-path pack: TRUNCATING f32x2 -> packed bf16 in ONE v_perm ----
__device__ __forceinline__ uint32_t pk2(float a, float b) {
    return __builtin_amdgcn_perm(__float_as_uint(b), __float_as_uint(a), 0x07060302u);
}
// relu on packed bf16 pair (bf16 bits as i16: negative iff float negative)
__device__ __forceinline__ uint32_t relu2(uint32_t x) {
    uint32_t r;
    asm("v_pk_max_i16 %0, %1, 0" : "=v"(r) : "v"(x));
    return r;
}
__device__ __forceinline__ uint32_t pk2r(float a, float b) { return relu2(pk2(a, b)); }
__device__ __forceinline__ uint16_t bfu(float v) { return (uint16_t)(__float_as_uint(v) >> 16); }

// producer storage permutation: f = sperm(s), swap bits [5:4] <-> [3:2]
__device__ __forceinline__ int sperm(int k) {
    return (k & 3) | (((k >> 2) & 3) << 4) | (((k >> 4) & 3) << 2);
}
// register-transpose permutation: hw-k -> storage-s after 4x permlane32_swap
// s = {k5, k3, k4, k2, k1, k0}
__device__ __forceinline__ int rperm(int k) {
    return (k & 32) | (((k >> 3) & 1) << 4) | (((k >> 4) & 1) << 3) | (k & 7);
}

// ---------------- prologue: pack 36 A-fragments into d_ws ----------------
// pm=0: plain k (LDS-fed layers: ws0, wc0). pm=2: register-transpose-fed
// layers (ws1, ws2, wc1, wc2, wc3): weight at hw-k = W[sperm(rperm(k))].
__global__ void pack_weights(const float* __restrict__ ws0, const float* __restrict__ ws1,
                             const float* __restrict__ ws2, const float* __restrict__ wc0,
                             const float* __restrict__ wc1, const float* __restrict__ wc2,
                             const float* __restrict__ wc3, uint4* __restrict__ wpack) {
    int idx = blockIdx.x * blockDim.x + threadIdx.x;
    if (idx >= NFRAGS * 64) return;
    int F = idx >> 6, cl = idx & 63, cm = cl & 15, cq = cl >> 4;
    const float* w; int IN, OUT, mt, ks, pm;
    if (F < 4)       { w = ws0; IN = 3;  OUT = 64; mt = F;            ks = 0;          pm = 0; }
    else if (F < 12) { w = ws1; IN = 64; OUT = 64; mt = (F-4) >> 1;   ks = (F-4) & 1;  pm = 2; }
    else if (F < 14) { w = ws2; IN = 64; OUT = 16; mt = 0;            ks = F - 12;     pm = 2; }
    else if (F < 18) { w = wc0; IN = 18; OUT = 64; mt = F - 14;       ks = 0;          pm = 0; }
    else if (F < 26) { w = wc1; IN = 64; OUT = 64; mt = (F-18) >> 1;  ks = (F-18) & 1; pm = 2; }
    else if (F < 34) { w = wc2; IN = 64; OUT = 64; mt = (F-26) >> 1;  ks = (F-26) & 1; pm = 2; }
    else             { w = wc3; IN = 64; OUT = 3;  mt = 0;            ks = F - 34;     pm = 2; }
    const int fo = mt * 16 + cm;
    uint32_t pk[4];
    for (int jj = 0; jj < 4; ++jj) {
        uint32_t h[2];
        for (int bb = 0; bb < 2; ++bb) {
            int kg = ks * 32 + cq * 8 + jj * 2 + bb;      // hw k position
            int kr = (pm == 2) ? sperm(rperm(kg)) : kg;   // source feature index
            float v = 0.f;
            if (fo < OUT && kr < IN) v = w[kr * OUT + fo];
            h[bb] = f2bf_rne(v);
        }
        pk[jj] = h[0] | (h[1] << 16);
    }
    wpack[F * 64 + cl] = make_uint4(pk[0], pk[1], pk[2], pk[3]);
}

// ---------------- main kernel ----------------
__global__ __launch_bounds__(BS, 8) void nerf_main(const float* __restrict__ xin,
                                                   const uint4* __restrict__ wpack,
                                                   float* __restrict__ outp, int n) {
    // LDS only for input staging and the L2 color-input assembly.
    __shared__ __align__(16) char smem[NW * T * 2048];
    const int tid = threadIdx.x, wv = tid >> 6, lane = tid & 63;
    const int p = lane & 15, q = lane >> 4;
    const int sw = p & 7;
    char* actw = smem + wv * (T * 2048);

    // inline address only (R5 lesson: runtime-indexed pointer arrays -> scratch)
    auto aaddr = [&](int t, int g) -> char* {
        return actw + t * 2048 + p * 128 + ((g ^ sw) << 4);
    };
    auto ldA = [&](int F) -> bf16x8 {
        uint4 u = wpack[F * 64 + lane];
        return *(bf16x8*)&u;
    };
    const f32x4 z4 = {0.f, 0.f, 0.f, 0.f};

    // D (4 m-tiles) -> pack+relu -> 4x v_permlane32_swap -> next layer's B frags.
    auto xpose = [&](const f32x4* d, bf16x8& b0, bf16x8& b1) {
        uint32_t X0 = pk2r(d[0][0], d[0][1]), X1 = pk2r(d[0][2], d[0][3]);
        uint32_t X2 = pk2r(d[1][0], d[1][1]), X3 = pk2r(d[1][2], d[1][3]);
        uint32_t X4 = pk2r(d[2][0], d[2][1]), X5 = pk2r(d[2][2], d[2][3]);
        uint32_t X6 = pk2r(d[3][0], d[3][1]), X7 = pk2r(d[3][2], d[3][3]);
        asm("v_permlane32_swap_b32 %0, %1" : "+v"(X0), "+v"(X4));
        asm("v_permlane32_swap_b32 %0, %1" : "+v"(X1), "+v"(X5));
        asm("v_permlane32_swap_b32 %0, %1" : "+v"(X2), "+v"(X6));
        asm("v_permlane32_swap_b32 %0, %1" : "+v"(X3), "+v"(X7));
        uint4 u0 = make_uint4(X0, X1, X2, X3), u1 = make_uint4(X4, X5, X6, X7);
        b0 = *(bf16x8*)&u0; b1 = *(bf16x8*)&u1;
    };

    const int stride_pts = gridDim.x * PTS_BLK;
    for (int base0 = blockIdx.x * PTS_BLK; base0 < n; base0 += stride_pts) {
        const int base = base0 + wv * (T * 16);

        // ---- staging: lane (p,q) stages tile q (q<T), point base+q*16+p ----
        float vv0 = 0.f, vv1 = 0.f, vv2 = 0.f;
        {
            float x0 = 0.f, x1 = 0.f, x2 = 0.f;
            const int pi = base + q * 16 + p;
            if (q < T && pi < n) {
                const float2* xp = (const float2*)(xin + (size_t)pi * 6);
                float2 a = xp[0], b = xp[1], c = xp[2];
                x0 = a.x; x1 = a.y; x2 = b.x; vv0 = b.y; vv1 = c.x; vv2 = c.y;
            }
            if (q < T) {
                *(uint4*)aaddr(q, 0) = make_uint4(pk2(x0, x1), pk2(x2, 0.f), 0u, 0u);
                *(uint4*)aaddr(q, 1) = make_uint4(0u, 0u, 0u, 0u);
                *(uint4*)aaddr(q, 2) = make_uint4(0u, 0u, 0u, 0u);
                *(uint4*)aaddr(q, 3) = make_uint4(0u, 0u, 0u, 0u);
            }
        }

        bf16x8 c0[T], c1[T];   // live activation fragments (register path)

        // ---- L0: sigma net 3->64 (K=32, frags 0..3), LDS-fed ----
        {
            bf16x8 A0 = ldA(0), A1 = ldA(1), A2 = ldA(2), A3 = ldA(3);
            bf16x8 b[T];
#pragma unroll
            for (int t = 0; t < T; ++t) b[t] = *(const bf16x8*)aaddr(t, q);
            f32x4 d[T][4];
#pragma unroll
            for (int t = 0; t < T; ++t) {
                d[t][0] = __builtin_amdgcn_mfma_f32_16x16x32_bf16(A0, b[t], z4, 0, 0, 0);
                d[t][1] = __builtin_amdgcn_mfma_f32_16x16x32_bf16(A1, b[t], z4, 0, 0, 0);
                d[t][2] = __builtin_amdgcn_mfma_f32_16x16x32_bf16(A2, b[t], z4, 0, 0, 0);
                d[t][3] = __builtin_amdgcn_mfma_f32_16x16x32_bf16(A3, b[t], z4, 0, 0, 0);
            }
#pragma unroll
            for (int t = 0; t < T; ++t) xpose(d[t], c0[t], c1[t]);
        }

        auto layer64 = [&](int FB) {
            bf16x8 A[8];
#pragma unroll
            for (int i = 0; i < 8; ++i) A[i] = ldA(FB + i);
            f32x4 d[T][4];
#pragma unroll
            for (int t = 0; t < T; ++t) {
#pragma unroll
                for (int mt = 0; mt < 4; ++mt) {
                    f32x4 acc = __builtin_amdgcn_mfma_f32_16x16x32_bf16(A[mt*2],   c0[t], z4,  0, 0, 0);
                    d[t][mt]  = __builtin_amdgcn_mfma_f32_16x16x32_bf16(A[mt*2+1], c1[t], acc, 0, 0, 0);
                }
            }
#pragma unroll
            for (int t = 0; t < T; ++t) xpose(d[t], c0[t], c1[t]);
        };

        // ---- L1: sigma net 64->64 (frags 4..11) ----
        layer64(4);

        // ---- L2: ws2 64->16 (frags 12,13): sigma + color-input assembly (LDS) ----
        float sig[T];
        {
            bf16x8 A0 = ldA(12), A1 = ldA(13);
            f32x4 d[T];
#pragma unroll
            for (int t = 0; t < T; ++t) {
                f32x4 acc = __builtin_amdgcn_mfma_f32_16x16x32_bf16(A0, c0[t], z4,  0, 0, 0);
                d[t]      = __builtin_amdgcn_mfma_f32_16x16x32_bf16(A1, c1[t], acc, 0, 0, 0);
            }
#pragma unroll
            for (int t = 0; t < T; ++t) {
                const float sx = d[t][0];                    // feat0 valid on q==0 lanes
                sig[t] = fmaxf(sx, 0.f) + __logf(1.f + __expf(-fabsf(sx)));
                // zero granules 0..3 collectively, then scatter (plain s = k layout)
                *(uint4*)aaddr(t, q) = make_uint4(0u, 0u, 0u, 0u);
                if (q == t) {   // views of point p, tile t live on lane (p, t)
                    *(uint32_t*)(aaddr(t, 0) + 0) = pk2(vv0, vv1);
                    *(uint16_t*)(aaddr(t, 0) + 4) = bfu(vv2);
                }
                // geo feats f=4q+r (f>=1) -> color k=f+2
                if (q == 0) {
                    *(uint16_t*)(aaddr(t, 0) + 6) = bfu(d[t][1]);
                    *(uint32_t*)(aaddr(t, 0) + 8) = pk2(d[t][2], d[t][3]);
                } else if (q == 1) {
                    *(uint32_t*)(aaddr(t, 0) + 12) = pk2(d[t][0], d[t][1]);
                    *(uint32_t*)(aaddr(t, 1) + 0)  = pk2(d[t][2], d[t][3]);
                } else if (q == 2) {
                    *(uint32_t*)(aaddr(t, 1) + 4) = pk2(d[t][0], d[t][1]);
                    *(uint32_t*)(aaddr(t, 1) + 8) = pk2(d[t][2], d[t][3]);
                } else {
                    *(uint32_t*)(aaddr(t, 1) + 12) = pk2(d[t][0], d[t][1]);
                    *(uint32_t*)(aaddr(t, 2) + 0)  = pk2(d[t][2], d[t][3]);
                }
            }
        }

        // ---- L3: wc0 18->64 (K=32, frags 14..17), LDS-fed ----
        {
            bf16x8 A0 = ldA(14), A1 = ldA(15), A2 = ldA(16), A3 = ldA(17);
            bf16x8 b[T];
#pragma unroll
            for (int t = 0; t < T; ++t) b[t] = *(const bf16x8*)aaddr(t, q);
            f32x4 d[T][4];
#pragma unroll
            for (int t = 0; t < T; ++t) {
                d[t][0] = __builtin_amdgcn_mfma_f32_16x16x32_bf16(A0, b[t], z4, 0, 0, 0);
                d[t][1] = __builtin_amdgcn_mfma_f32_16x16x32_bf16(A1, b[t], z4, 0, 0, 0);
                d[t][2] = __builtin_amdgcn_mfma_f32_16x16x32_bf16(A2, b[t], z4, 0, 0, 0);
                d[t][3] = __builtin_amdgcn_mfma_f32_16x16x32_bf16(A3, b[t], z4, 0, 0, 0);
            }
#pragma unroll
            for (int t = 0; t < T; ++t) xpose(d[t], c0[t], c1[t]);
        }

        // ---- L4, L5: wc1, wc2 64->64 ----
        layer64(18);
        layer64(26);

        // ---- L6: wc3 64->3 (frags 34,35) + output ----
        {
            bf16x8 A0 = ldA(34), A1 = ldA(35);
#pragma unroll
            for (int t = 0; t < T; ++t) {
                f32x4 acc = __builtin_amdgcn_mfma_f32_16x16x32_bf16(A0, c0[t], z4,  0, 0, 0);
                f32x4 d   = __builtin_amdgcn_mfma_f32_16x16x32_bf16(A1, c1[t], acc, 0, 0, 0);
                if (q == 0) {
                    const int pt = base + t * 16 + p;
                    if (pt < n)
                        *(float4*)(outp + (size_t)pt * 4) = make_float4(d[0], d[1], d[2], sig[t]);
                }
            }
        }
    }
}

extern "C" void kernel_launch(void* const* d_in, const int* in_sizes, int n_in,
                              void* d_out, int out_size, void* d_ws, size_t ws_size,
                              hipStream_t stream) {
    const float* x   = (const float*)d_in[0];
    const float* ws0 = (const float*)d_in[1];
    const float* ws1 = (const float*)d_in[2];
    const float* ws2 = (const float*)d_in[3];
    const float* wc0 = (const float*)d_in[4];
    const float* wc1 = (const float*)d_in[5];
    const float* wc2 = (const float*)d_in[6];
    const float* wc3 = (const float*)d_in[7];
    float* out = (float*)d_out;
    uint4* wpack = (uint4*)d_ws;

    const int n = in_sizes[0] / 6;
    pack_weights<<<(NFRAGS * 64 + 255) / 256, 256, 0, stream>>>(ws0, ws1, ws2, wc0, wc1, wc2, wc3, wpack);
    int grid = (n + PTS_BLK * PASSES - 1) / (PTS_BLK * PASSES);
    nerf_main<<<grid, BS, 0, stream>>>(x, wpack, out, n);
}

// Round 11
// 117.555 us; speedup vs baseline: 3.7041x; 3.7041x over previous
//
#include <hip/hip_runtime.h>
#include <math.h>
#include <stdint.h>

typedef short bf16x8 __attribute__((ext_vector_type(8)));   // 8 bf16 (4 VGPRs)
typedef float f32x4 __attribute__((ext_vector_type(4)));

#define NFRAGS 36
#define T 3                 // point-tiles (16 pts) per wave — 3 independent chains
#define NW 4                // waves per block
#define BS 256
#define PTS_BLK (NW * T * 16)   // 192 points per block

// RNE float -> bf16 bits (prologue only; weights keep full rounding quality)
__device__ __forceinline__ uint32_t f2bf_rne(float f) {
    uint32_t u = __float_as_uint(f);
    return (u + 0x7FFFu + ((u >> 16) & 1u)) >> 16;
}

// ---- hot-path pack: TRUNCATING f32x2 -> packed bf16 in ONE v_perm ----
__device__ __forceinline__ uint32_t pk2(float a, float b) {
    return __builtin_amdgcn_perm(__float_as_uint(b), __float_as_uint(a), 0x07060302u);
}
// relu on packed bf16 pair (bf16 bits as i16: negative iff float negative)
__device__ __forceinline__ uint32_t relu2(uint32_t x) {
    uint32_t r;
    asm("v_pk_max_i16 %0, %1, 0" : "=v"(r) : "v"(x));
    return r;
}
__device__ __forceinline__ uint32_t pk2r(float a, float b) { return relu2(pk2(a, b)); }
__device__ __forceinline__ uint16_t bfu(float v) { return (uint16_t)(__float_as_uint(v) >> 16); }

// producer storage permutation: f = sperm(s), swap bits [5:4] <-> [3:2]
__device__ __forceinline__ int sperm(int k) {
    return (k & 3) | (((k >> 2) & 3) << 4) | (((k >> 4) & 3) << 2);
}
// register-transpose permutation: hw-k -> storage-s after 4x permlane32_swap
// s = {k5, k3, k4, k2, k1, k0}
__device__ __forceinline__ int rperm(int k) {
    return (k & 32) | (((k >> 3) & 1) << 4) | (((k >> 4) & 1) << 3) | (k & 7);
}

// ---------------- prologue: pack 36 A-fragments into d_ws ----------------
// pm=0: plain k (LDS-fed layers: ws0, wc0). pm=2: register-transpose-fed
// layers (ws1, ws2, wc1, wc2, wc3): weight at hw-k = W[sperm(rperm(k))].
__global__ void pack_weights(const float* __restrict__ ws0, const float* __restrict__ ws1,
                             const float* __restrict__ ws2, const float* __restrict__ wc0,
                             const float* __restrict__ wc1, const float* __restrict__ wc2,
                             const float* __restrict__ wc3, uint4* __restrict__ wpack) {
    int idx = blockIdx.x * blockDim.x + threadIdx.x;
    if (idx >= NFRAGS * 64) return;
    int F = idx >> 6, cl = idx & 63, cm = cl & 15, cq = cl >> 4;
    const float* w; int IN, OUT, mt, ks, pm;
    if (F < 4)       { w = ws0; IN = 3;  OUT = 64; mt = F;            ks = 0;          pm = 0; }
    else if (F < 12) { w = ws1; IN = 64; OUT = 64; mt = (F-4) >> 1;   ks = (F-4) & 1;  pm = 2; }
    else if (F < 14) { w = ws2; IN = 64; OUT = 16; mt = 0;            ks = F - 12;     pm = 2; }
    else if (F < 18) { w = wc0; IN = 18; OUT = 64; mt = F - 14;       ks = 0;          pm = 0; }
    else if (F < 26) { w = wc1; IN = 64; OUT = 64; mt = (F-18) >> 1;  ks = (F-18) & 1; pm = 2; }
    else if (F < 34) { w = wc2; IN = 64; OUT = 64; mt = (F-26) >> 1;  ks = (F-26) & 1; pm = 2; }
    else             { w = wc3; IN = 64; OUT = 3;  mt = 0;            ks = F - 34;     pm = 2; }
    const int fo = mt * 16 + cm;
    uint32_t pk[4];
    for (int jj = 0; jj < 4; ++jj) {
        uint32_t h[2];
        for (int bb = 0; bb < 2; ++bb) {
            int kg = ks * 32 + cq * 8 + jj * 2 + bb;      // hw k position
            int kr = (pm == 2) ? sperm(rperm(kg)) : kg;   // source feature index
            float v = 0.f;
            if (fo < OUT && kr < IN) v = w[kr * OUT + fo];
            h[bb] = f2bf_rne(v);
        }
        pk[jj] = h[0] | (h[1] << 16);
    }
    wpack[F * 64 + cl] = make_uint4(pk[0], pk[1], pk[2], pk[3]);
}

// ---------------- main kernel ----------------
// launch_bounds(BS,4): 128-VGPR budget. NEVER request more waves/EU here:
// R10 (,8) capped VGPR at 32 -> 1.2 GB scratch spill, 7x regression.
__global__ __launch_bounds__(BS, 4) void nerf_main(const float* __restrict__ xin,
                                                   const uint4* __restrict__ wpack,
                                                   float* __restrict__ outp, int n) {
    // LDS only for input staging and the L2 color-input assembly.
    __shared__ __align__(16) char smem[NW * T * 2048];
    const int tid = threadIdx.x, wv = tid >> 6, lane = tid & 63;
    const int p = lane & 15, q = lane >> 4;
    const int sw = p & 7;
    char* actw = smem + wv * (T * 2048);
    const int base = blockIdx.x * PTS_BLK + wv * (T * 16);

    // inline address only (R5 lesson: runtime-indexed pointer arrays -> scratch)
    auto aaddr = [&](int t, int g) -> char* {
        return actw + t * 2048 + p * 128 + ((g ^ sw) << 4);
    };
    auto ldA = [&](int F) -> bf16x8 {
        uint4 u = wpack[F * 64 + lane];
        return *(bf16x8*)&u;
    };
    const f32x4 z4 = {0.f, 0.f, 0.f, 0.f};

    // D (4 m-tiles) -> pack+relu -> 4x v_permlane32_swap -> next layer's B frags.
    auto xpose = [&](const f32x4* d, bf16x8& b0, bf16x8& b1) {
        uint32_t X0 = pk2r(d[0][0], d[0][1]), X1 = pk2r(d[0][2], d[0][3]);
        uint32_t X2 = pk2r(d[1][0], d[1][1]), X3 = pk2r(d[1][2], d[1][3]);
        uint32_t X4 = pk2r(d[2][0], d[2][1]), X5 = pk2r(d[2][2], d[2][3]);
        uint32_t X6 = pk2r(d[3][0], d[3][1]), X7 = pk2r(d[3][2], d[3][3]);
        asm("v_permlane32_swap_b32 %0, %1" : "+v"(X0), "+v"(X4));
        asm("v_permlane32_swap_b32 %0, %1" : "+v"(X1), "+v"(X5));
        asm("v_permlane32_swap_b32 %0, %1" : "+v"(X2), "+v"(X6));
        asm("v_permlane32_swap_b32 %0, %1" : "+v"(X3), "+v"(X7));
        uint4 u0 = make_uint4(X0, X1, X2, X3), u1 = make_uint4(X4, X5, X6, X7);
        b0 = *(bf16x8*)&u0; b1 = *(bf16x8*)&u1;
    };

    // ---- staging: lane (p,q) stages tile q (q<T), point base+q*16+p ----
    float vv0 = 0.f, vv1 = 0.f, vv2 = 0.f;
    {
        float x0 = 0.f, x1 = 0.f, x2 = 0.f;
        const int pi = base + q * 16 + p;
        if (q < T && pi < n) {
            const float2* xp = (const float2*)(xin + (size_t)pi * 6);
            float2 a = xp[0], b = xp[1], c = xp[2];
            x0 = a.x; x1 = a.y; x2 = b.x; vv0 = b.y; vv1 = c.x; vv2 = c.y;
        }
        if (q < T) {
            *(uint4*)aaddr(q, 0) = make_uint4(pk2(x0, x1), pk2(x2, 0.f), 0u, 0u);
            *(uint4*)aaddr(q, 1) = make_uint4(0u, 0u, 0u, 0u);
            *(uint4*)aaddr(q, 2) = make_uint4(0u, 0u, 0u, 0u);
            *(uint4*)aaddr(q, 3) = make_uint4(0u, 0u, 0u, 0u);
        }
    }

    bf16x8 c0[T], c1[T];   // live activation fragments (register path)

    // ---- L0: sigma net 3->64 (K=32, frags 0..3), LDS-fed ----
    {
        bf16x8 A0 = ldA(0), A1 = ldA(1), A2 = ldA(2), A3 = ldA(3);
        bf16x8 b[T];
#pragma unroll
        for (int t = 0; t < T; ++t) b[t] = *(const bf16x8*)aaddr(t, q);
        f32x4 d[T][4];
#pragma unroll
        for (int t = 0; t < T; ++t) {
            d[t][0] = __builtin_amdgcn_mfma_f32_16x16x32_bf16(A0, b[t], z4, 0, 0, 0);
            d[t][1] = __builtin_amdgcn_mfma_f32_16x16x32_bf16(A1, b[t], z4, 0, 0, 0);
            d[t][2] = __builtin_amdgcn_mfma_f32_16x16x32_bf16(A2, b[t], z4, 0, 0, 0);
            d[t][3] = __builtin_amdgcn_mfma_f32_16x16x32_bf16(A3, b[t], z4, 0, 0, 0);
        }
#pragma unroll
        for (int t = 0; t < T; ++t) xpose(d[t], c0[t], c1[t]);
    }

    auto layer64 = [&](int FB) {
        bf16x8 A[8];
#pragma unroll
        for (int i = 0; i < 8; ++i) A[i] = ldA(FB + i);
        f32x4 d[T][4];
#pragma unroll
        for (int t = 0; t < T; ++t) {
#pragma unroll
            for (int mt = 0; mt < 4; ++mt) {
                f32x4 acc = __builtin_amdgcn_mfma_f32_16x16x32_bf16(A[mt*2],   c0[t], z4,  0, 0, 0);
                d[t][mt]  = __builtin_amdgcn_mfma_f32_16x16x32_bf16(A[mt*2+1], c1[t], acc, 0, 0, 0);
            }
        }
#pragma unroll
        for (int t = 0; t < T; ++t) xpose(d[t], c0[t], c1[t]);
    };

    // ---- L1: sigma net 64->64 (frags 4..11) ----
    layer64(4);

    // ---- L2: ws2 64->16 (frags 12,13): sigma + color-input assembly (LDS) ----
    float sig[T];
    {
        bf16x8 A0 = ldA(12), A1 = ldA(13);
        f32x4 d[T];
#pragma unroll
        for (int t = 0; t < T; ++t) {
            f32x4 acc = __builtin_amdgcn_mfma_f32_16x16x32_bf16(A0, c0[t], z4,  0, 0, 0);
            d[t]      = __builtin_amdgcn_mfma_f32_16x16x32_bf16(A1, c1[t], acc, 0, 0, 0);
        }
#pragma unroll
        for (int t = 0; t < T; ++t) {
            const float sx = d[t][0];                    // feat0 valid on q==0 lanes
            sig[t] = fmaxf(sx, 0.f) + __logf(1.f + __expf(-fabsf(sx)));
            // zero granules 0..3 collectively, then scatter (plain s = k layout)
            *(uint4*)aaddr(t, q) = make_uint4(0u, 0u, 0u, 0u);
            if (q == t) {   // views of point p, tile t live on lane (p, t)
                *(uint32_t*)(aaddr(t, 0) + 0) = pk2(vv0, vv1);
                *(uint16_t*)(aaddr(t, 0) + 4) = bfu(vv2);
            }
            // geo feats f=4q+r (f>=1) -> color k=f+2
            if (q == 0) {
                *(uint16_t*)(aaddr(t, 0) + 6) = bfu(d[t][1]);
                *(uint32_t*)(aaddr(t, 0) + 8) = pk2(d[t][2], d[t][3]);
            } else if (q == 1) {
                *(uint32_t*)(aaddr(t, 0) + 12) = pk2(d[t][0], d[t][1]);
                *(uint32_t*)(aaddr(t, 1) + 0)  = pk2(d[t][2], d[t][3]);
            } else if (q == 2) {
                *(uint32_t*)(aaddr(t, 1) + 4) = pk2(d[t][0], d[t][1]);
                *(uint32_t*)(aaddr(t, 1) + 8) = pk2(d[t][2], d[t][3]);
            } else {
                *(uint32_t*)(aaddr(t, 1) + 12) = pk2(d[t][0], d[t][1]);
                *(uint32_t*)(aaddr(t, 2) + 0)  = pk2(d[t][2], d[t][3]);
            }
        }
    }

    // ---- L3: wc0 18->64 (K=32, frags 14..17), LDS-fed ----
    {
        bf16x8 A0 = ldA(14), A1 = ldA(15), A2 = ldA(16), A3 = ldA(17);
        bf16x8 b[T];
#pragma unroll
        for (int t = 0; t < T; ++t) b[t] = *(const bf16x8*)aaddr(t, q);
        f32x4 d[T][4];
#pragma unroll
        for (int t = 0; t < T; ++t) {
            d[t][0] = __builtin_amdgcn_mfma_f32_16x16x32_bf16(A0, b[t], z4, 0, 0, 0);
            d[t][1] = __builtin_amdgcn_mfma_f32_16x16x32_bf16(A1, b[t], z4, 0, 0, 0);
            d[t][2] = __builtin_amdgcn_mfma_f32_16x16x32_bf16(A2, b[t], z4, 0, 0, 0);
            d[t][3] = __builtin_amdgcn_mfma_f32_16x16x32_bf16(A3, b[t], z4, 0, 0, 0);
        }
#pragma unroll
        for (int t = 0; t < T; ++t) xpose(d[t], c0[t], c1[t]);
    }

    // ---- L4, L5: wc1, wc2 64->64 ----
    layer64(18);
    layer64(26);

    // ---- L6: wc3 64->3 (frags 34,35) + output ----
    {
        bf16x8 A0 = ldA(34), A1 = ldA(35);
#pragma unroll
        for (int t = 0; t < T; ++t) {
            f32x4 acc = __builtin_amdgcn_mfma_f32_16x16x32_bf16(A0, c0[t], z4,  0, 0, 0);
            f32x4 d   = __builtin_amdgcn_mfma_f32_16x16x32_bf16(A1, c1[t], acc, 0, 0, 0);
            if (q == 0) {
                const int pt = base + t * 16 + p;
                if (pt < n)
                    *(float4*)(outp + (size_t)pt * 4) = make_float4(d[0], d[1], d[2], sig[t]);
            }
        }
    }
}

extern "C" void kernel_launch(void* const* d_in, const int* in_sizes, int n_in,
                              void* d_out, int out_size, void* d_ws, size_t ws_size,
                              hipStream_t stream) {
    const float* x   = (const float*)d_in[0];
    const float* ws0 = (const float*)d_in[1];
    const float* ws1 = (const float*)d_in[2];
    const float* ws2 = (const float*)d_in[3];
    const float* wc0 = (const float*)d_in[4];
    const float* wc1 = (const float*)d_in[5];
    const float* wc2 = (const float*)d_in[6];
    const float* wc3 = (const float*)d_in[7];
    float* out = (float*)d_out;
    uint4* wpack = (uint4*)d_ws;

    const int n = in_sizes[0] / 6;
    pack_weights<<<(NFRAGS * 64 + 255) / 256, 256, 0, stream>>>(ws0, ws1, ws2, wc0, wc1, wc2, wc3, wpack);
    const int grid = (n + PTS_BLK - 1) / PTS_BLK;
    nerf_main<<<grid, BS, 0, stream>>>(x, wpack, out, n);
}